// Round 1
// baseline (6564.968 us; speedup 1.0000x reference)
//
#include <hip/hip_runtime.h>

typedef __attribute__((ext_vector_type(8))) short short8;
typedef __attribute__((ext_vector_type(4))) float f32x4;

__device__ __forceinline__ unsigned short f2bf(float f) {
  unsigned int u = __float_as_uint(f);
  u = (u + 0x7fffu + ((u >> 16) & 1u)) >> 16;
  return (unsigned short)u;
}

__device__ __forceinline__ void xp_store(float* p, float v) { *p = v; }
__device__ __forceinline__ void xp_store(unsigned short* p, float v) { *p = f2bf(v); }
__device__ __forceinline__ float xp_load(const float* p) { return *p; }
__device__ __forceinline__ float xp_load(const unsigned short* p) {
  return __uint_as_float(((unsigned int)*p) << 16);
}

// ---------------- prep: pack W_x (f32 -> bf16 pairs), layout (1024 rows, 128 dwords) ----
__global__ void prep_wx(const float* __restrict__ W, unsigned int* __restrict__ Wx2) {
  int i = blockIdx.x * 256 + threadIdx.x;  // 1024*128 dwords
  int g = i >> 7, kk = i & 127;
  float lo = W[(size_t)g * 512 + 256 + 2 * kk];
  float hi = W[(size_t)g * 512 + 256 + 2 * kk + 1];
  Wx2[i] = (unsigned int)f2bf(lo) | ((unsigned int)f2bf(hi) << 16);
}

// ---------------- GEMM: xp[m][g] = sum_k x[m][k] * Wx[g][k] + b[g] ----------------
// M=65536, N=1024, K=256. 128x128 tile, 4 waves, 16x16x32 bf16 MFMA.
template <typename XPT>
__global__ __launch_bounds__(256, 4) void gemm_xp(const float* __restrict__ x,
                                                  const unsigned int* __restrict__ Wx2,
                                                  const float* __restrict__ bias,
                                                  XPT* __restrict__ xp) {
  __shared__ unsigned short As[128][40];  // bf16, padded stride (80B: 16B-aligned, ~2-way banks)
  __shared__ unsigned short Bs[128][40];
  const int m0 = blockIdx.y * 128, n0 = blockIdx.x * 128;
  const int tid = threadIdx.x, lane = tid & 63, w = tid >> 6;
  const int wr = w >> 1, wc = w & 1;
  const int r16 = lane & 15, kq = lane >> 4;  // kq in 0..3
  f32x4 acc[4][4];
#pragma unroll
  for (int m = 0; m < 4; m++)
#pragma unroll
    for (int n = 0; n < 4; n++)
#pragma unroll
      for (int j = 0; j < 4; j++) acc[m][n][j] = 0.f;

  for (int kb = 0; kb < 256; kb += 32) {
    __syncthreads();
// stage A: 128 rows x 32 k, f32 -> bf16
#pragma unroll
    for (int i = 0; i < 4; i++) {
      int idx = tid + i * 256;
      int row = idx >> 3, c4 = idx & 7;
      float4 v = *(const float4*)(x + (size_t)(m0 + row) * 256 + kb + c4 * 4);
      ushort4 s;
      s.x = f2bf(v.x); s.y = f2bf(v.y); s.z = f2bf(v.z); s.w = f2bf(v.w);
      *(ushort4*)&As[row][c4 * 4] = s;
    }
// stage B: 128 gate-rows x 32 k (already bf16-packed dwords)
#pragma unroll
    for (int i = 0; i < 2; i++) {
      int idx = tid + i * 256;
      int row = idx >> 2, c = idx & 3;
      uint4 v = *(const uint4*)(Wx2 + (size_t)(n0 + row) * 128 + (kb >> 1) + c * 4);
      *(uint4*)&Bs[row][c * 8] = v;
    }
    __syncthreads();
    short8 a[4], bb[4];
#pragma unroll
    for (int m = 0; m < 4; m++)
      a[m] = *(const short8*)&As[wr * 64 + m * 16 + r16][kq * 8];
#pragma unroll
    for (int n = 0; n < 4; n++)
      bb[n] = *(const short8*)&Bs[wc * 64 + n * 16 + r16][kq * 8];
#pragma unroll
    for (int m = 0; m < 4; m++)
#pragma unroll
      for (int n = 0; n < 4; n++)
        acc[m][n] = __builtin_amdgcn_mfma_f32_16x16x32_bf16(a[m], bb[n], acc[m][n], 0, 0, 0);
  }
// epilogue: D layout col=lane&15, row=(lane>>4)*4+j  [m89-verified]
#pragma unroll
  for (int n = 0; n < 4; n++) {
    int gn = n0 + wc * 64 + n * 16 + r16;
    float bi = bias[gn];
#pragma unroll
    for (int m = 0; m < 4; m++) {
      int gm = m0 + wr * 64 + m * 16 + kq * 4;
#pragma unroll
      for (int j = 0; j < 4; j++) {
        xp_store(&xp[(size_t)(gm + j) * 1024 + gn], acc[m][n][j] + bi);
      }
    }
  }
}

// ---------------- recurrence: 4 WGs per batch, f32 weights VGPR-resident -------------
// WG q of batch b owns hidden units [q*64, q*64+64) i.e. gate rows {gt*256+q*64+u}.
// Local row lr in [0,256): gt = lr>>6, u = lr&63.  512 threads: ks=tid&7 (K-slice of 32),
// rq=tid>>3 (4 rows lr=rq*4+r). Weight chunks stored rotated by ks so LDS h reads are
// conflict-free across ks groups.
template <typename XPT>
__global__ __launch_bounds__(512, 2) void lstm_rec(const float* __restrict__ W,
                                                   const XPT* __restrict__ xp,
                                                   float* __restrict__ out,
                                                   float* __restrict__ hbuf,
                                                   unsigned int* __restrict__ ctr) {
  __shared__ float h_s[256];
  __shared__ float gate[256];
  const int tid = threadIdx.x;
  const int b = blockIdx.x & 63, q = blockIdx.x >> 6;
  const int ks = tid & 7, rq = tid >> 3;

  float w[4][32];
#pragma unroll
  for (int r = 0; r < 4; r++) {
    const int lr = rq * 4 + r;
    const int G = ((lr >> 6) << 8) + (q << 6) + (lr & 63);
    const float* wrow = W + (size_t)G * 512 + ks * 32;
#pragma unroll
    for (int j = 0; j < 8; j++) {
      const int ch = (j + ks) & 7;
      float4 v = *(const float4*)(wrow + ch * 4);
      w[r][j * 4 + 0] = v.x;
      w[r][j * 4 + 1] = v.y;
      w[r][j * 4 + 2] = v.z;
      w[r][j * 4 + 3] = v.w;
    }
  }

  if (tid < 256) h_s[tid] = 0.f;
  float c = 0.f;
  const size_t xpb = (size_t)b << 10;
  float xpv[4] = {0.f, 0.f, 0.f, 0.f};
  if (tid < 64) {
#pragma unroll
    for (int g = 0; g < 4; g++)
      xpv[g] = xp_load(&xp[xpb * 1024 + g * 256 + (q << 6) + tid]);
  }
  unsigned int* myctr = &ctr[b * 32];
  __syncthreads();

  for (int t = 0; t < 1024; t++) {
    // prefetch next step's xp row (latency hidden under the dot)
    float xpn[4] = {0.f, 0.f, 0.f, 0.f};
    if (tid < 64 && t < 1023) {
#pragma unroll
      for (int g = 0; g < 4; g++)
        xpn[g] = xp_load(&xp[(xpb + t + 1) * 1024 + g * 256 + (q << 6) + tid]);
    }
    // dot: 4 rows x 32-K-slice per thread, rotated LDS chunks (conflict-free broadcast)
    float a0 = 0.f, a1 = 0.f, a2 = 0.f, a3 = 0.f;
#pragma unroll
    for (int j = 0; j < 8; j++) {
      const int ch = (j + ks) & 7;
      const f32x4 hv = *(const f32x4*)&h_s[(ks << 5) + (ch << 2)];
#pragma unroll
      for (int m = 0; m < 4; m++) {
        a0 = fmaf(w[0][j * 4 + m], hv[m], a0);
        a1 = fmaf(w[1][j * 4 + m], hv[m], a1);
        a2 = fmaf(w[2][j * 4 + m], hv[m], a2);
        a3 = fmaf(w[3][j * 4 + m], hv[m], a3);
      }
    }
// reduce across the 8 ks lanes (adjacent lanes, intra-wave)
#pragma unroll
    for (int d = 1; d < 8; d <<= 1) {
      a0 += __shfl_xor(a0, d, 64);
      a1 += __shfl_xor(a1, d, 64);
      a2 += __shfl_xor(a2, d, 64);
      a3 += __shfl_xor(a3, d, 64);
    }
    if (ks == 0) {
      f32x4 gv = {a0, a1, a2, a3};
      *(f32x4*)&gate[rq << 2] = gv;
    }
    __syncthreads();
    if (tid < 64) {
      float gf = gate[tid] + xpv[0];
      float gi = gate[64 + tid] + xpv[1];
      float gg = gate[128 + tid] + xpv[2];
      float go = gate[192 + tid] + xpv[3];
      float f = 1.f / (1.f + __expf(-gf));
      float ii = 1.f / (1.f + __expf(-gi));
      float eg = __expf(2.f * gg);
      float gt = (eg - 1.f) / (eg + 1.f);
      float o = 1.f / (1.f + __expf(-go));
      c = f * c + ii * gt;
      float ec = __expf(2.f * c);
      float tc = (ec - 1.f) / (ec + 1.f);
      float h = o * tc;
      out[(xpb + t) * 256 + (q << 6) + tid] = h;
      hbuf[(size_t)((b << 1) + (t & 1)) * 256 + (q << 6) + tid] = h;
      if (t == 1023) {
        out[16777216 + b * 256 + (q << 6) + tid] = h;  // h_fin
        out[16777216 + 16384 + b * 256 + (q << 6) + tid] = c;  // c_fin
      }
      xpv[0] = xpn[0]; xpv[1] = xpn[1]; xpv[2] = xpn[2]; xpv[3] = xpn[3];
    }
    __syncthreads();  // drains hbuf stores (per-wave vmcnt(0) before s_barrier)
    if (tid == 0) {
      __hip_atomic_fetch_add(myctr, 1u, __ATOMIC_RELEASE, __HIP_MEMORY_SCOPE_AGENT);
      const unsigned int tgt = 4u * (unsigned int)(t + 1);
      while (__hip_atomic_load(myctr, __ATOMIC_ACQUIRE, __HIP_MEMORY_SCOPE_AGENT) < tgt) {
      }
    }
    __syncthreads();
    if (tid < 256) h_s[tid] = hbuf[(size_t)((b << 1) + (t & 1)) * 256 + tid];
    __syncthreads();
  }
}

extern "C" void kernel_launch(void* const* d_in, const int* in_sizes, int n_in,
                              void* d_out, int out_size, void* d_ws, size_t ws_size,
                              hipStream_t stream) {
  (void)in_sizes; (void)n_in; (void)out_size;
  const float* x = (const float*)d_in[0];
  const float* W = (const float*)d_in[1];
  const float* bias = (const float*)d_in[2];
  float* out = (float*)d_out;
  char* ws = (char*)d_ws;

  unsigned int* Wx2 = (unsigned int*)ws;            // 524288 B
  float* hbuf = (float*)(ws + 524288);              // 131072 B
  unsigned int* ctr = (unsigned int*)(ws + 655360); // 8192 B
  char* xpmem = ws + 1048576;

  const size_t need32 = 1048576 + (size_t)65536 * 1024 * 4;

  hipMemsetAsync(ctr, 0, 8192, stream);
  prep_wx<<<512, 256, 0, stream>>>(W, Wx2);

  if (ws_size >= need32) {
    gemm_xp<float><<<dim3(8, 512), 256, 0, stream>>>(x, Wx2, bias, (float*)xpmem);
    lstm_rec<float><<<256, 512, 0, stream>>>(W, (const float*)xpmem, out, hbuf, ctr);
  } else {
    gemm_xp<unsigned short><<<dim3(8, 512), 256, 0, stream>>>(x, Wx2, bias,
                                                              (unsigned short*)xpmem);
    lstm_rec<unsigned short><<<256, 512, 0, stream>>>(W, (const unsigned short*)xpmem, out,
                                                      hbuf, ctr);
  }
}

// Round 2
// 5117.900 us; speedup vs baseline: 1.2827x; 1.2827x over previous
//
#include <hip/hip_runtime.h>

typedef __attribute__((ext_vector_type(8))) short short8;
typedef __attribute__((ext_vector_type(4))) float f32x4;

__device__ __forceinline__ unsigned short f2bf(float f) {
  unsigned int u = __float_as_uint(f);
  u = (u + 0x7fffu + ((u >> 16) & 1u)) >> 16;
  return (unsigned short)u;
}

__device__ __forceinline__ void xp_store(float* p, float v) { *p = v; }
__device__ __forceinline__ void xp_store(unsigned short* p, float v) { *p = f2bf(v); }
__device__ __forceinline__ float xp_load(const float* p) { return *p; }
__device__ __forceinline__ float xp_load(const unsigned short* p) {
  return __uint_as_float(((unsigned int)*p) << 16);
}

// ---------------- prep: pack W_x (f32 -> bf16 pairs), layout (1024 rows, 128 dwords) ----
__global__ void prep_wx(const float* __restrict__ W, unsigned int* __restrict__ Wx2) {
  int i = blockIdx.x * 256 + threadIdx.x;  // 1024*128 dwords
  int g = i >> 7, kk = i & 127;
  float lo = W[(size_t)g * 512 + 256 + 2 * kk];
  float hi = W[(size_t)g * 512 + 256 + 2 * kk + 1];
  Wx2[i] = (unsigned int)f2bf(lo) | ((unsigned int)f2bf(hi) << 16);
}

// ---------------- GEMM: xp[m][g] = sum_k x[m][k] * Wx[g][k] + b[g] ----------------
template <typename XPT>
__global__ __launch_bounds__(256, 4) void gemm_xp(const float* __restrict__ x,
                                                  const unsigned int* __restrict__ Wx2,
                                                  const float* __restrict__ bias,
                                                  XPT* __restrict__ xp) {
  __shared__ unsigned short As[128][40];
  __shared__ unsigned short Bs[128][40];
  const int m0 = blockIdx.y * 128, n0 = blockIdx.x * 128;
  const int tid = threadIdx.x, lane = tid & 63, w = tid >> 6;
  const int wr = w >> 1, wc = w & 1;
  const int r16 = lane & 15, kq = lane >> 4;
  f32x4 acc[4][4];
#pragma unroll
  for (int m = 0; m < 4; m++)
#pragma unroll
    for (int n = 0; n < 4; n++)
#pragma unroll
      for (int j = 0; j < 4; j++) acc[m][n][j] = 0.f;

  for (int kb = 0; kb < 256; kb += 32) {
    __syncthreads();
#pragma unroll
    for (int i = 0; i < 4; i++) {
      int idx = tid + i * 256;
      int row = idx >> 3, c4 = idx & 7;
      float4 v = *(const float4*)(x + (size_t)(m0 + row) * 256 + kb + c4 * 4);
      ushort4 s;
      s.x = f2bf(v.x); s.y = f2bf(v.y); s.z = f2bf(v.z); s.w = f2bf(v.w);
      *(ushort4*)&As[row][c4 * 4] = s;
    }
#pragma unroll
    for (int i = 0; i < 2; i++) {
      int idx = tid + i * 256;
      int row = idx >> 2, c = idx & 3;
      uint4 v = *(const uint4*)(Wx2 + (size_t)(n0 + row) * 128 + (kb >> 1) + c * 4);
      *(uint4*)&Bs[row][c * 8] = v;
    }
    __syncthreads();
    short8 a[4], bb[4];
#pragma unroll
    for (int m = 0; m < 4; m++)
      a[m] = *(const short8*)&As[wr * 64 + m * 16 + r16][kq * 8];
#pragma unroll
    for (int n = 0; n < 4; n++)
      bb[n] = *(const short8*)&Bs[wc * 64 + n * 16 + r16][kq * 8];
#pragma unroll
    for (int m = 0; m < 4; m++)
#pragma unroll
      for (int n = 0; n < 4; n++)
        acc[m][n] = __builtin_amdgcn_mfma_f32_16x16x32_bf16(a[m], bb[n], acc[m][n], 0, 0, 0);
  }
#pragma unroll
  for (int n = 0; n < 4; n++) {
    int gn = n0 + wc * 64 + n * 16 + r16;
    float bi = bias[gn];
#pragma unroll
    for (int m = 0; m < 4; m++) {
      int gm = m0 + wr * 64 + m * 16 + kq * 4;
#pragma unroll
      for (int j = 0; j < 4; j++) {
        xp_store(&xp[(size_t)(gm + j) * 1024 + gn], acc[m][n][j] + bi);
      }
    }
  }
}

// ---------------- recurrence ------------------------------------------------------
// 4 WGs per batch; WG q owns units [q*64, q*64+64). Thread (u = tid>>3, ks = tid&7)
// owns ALL FOUR gate rows of unit u over K-slice [ks*32, ks*32+32): after the 3-round
// intra-wave butterfly every lane holds the unit's complete f,i,g,o -> in-register
// c/h update (redundant across the 8 ks lanes, deterministic). h is exchanged through
// hbuf with RELAXED agent-scope atomics only (cache-bypassing, no invalidates):
//   stores -> __syncthreads (compiler drains vmcnt(0) per wave) -> tid0 relaxed add
//   readers: wave-broadcast relaxed poll of the counter, then relaxed loads of h.
// Leader/laggard skew <= 1 (counting argument), so the 2-slot hbuf is race-free.
template <typename XPT>
__global__ __launch_bounds__(512, 2) void lstm_rec(const float* __restrict__ W,
                                                   const XPT* __restrict__ xp,
                                                   float* __restrict__ out,
                                                   float* __restrict__ hbuf,
                                                   unsigned int* __restrict__ ctr) {
  const int tid = threadIdx.x;
  const int b = blockIdx.x & 63, q = blockIdx.x >> 6;
  const int ks = tid & 7, u = tid >> 3;
  const int lane = tid & 63, wv = tid >> 6;
  const int gu = (q << 6) + u;  // global hidden unit

  // weights: 4 gate rows x 32 K-slice, f32, register-resident
  float w[4][32];
#pragma unroll
  for (int g = 0; g < 4; g++) {
    const float* rp = W + (size_t)(g * 256 + gu) * 512 + (ks << 5);
#pragma unroll
    for (int i = 0; i < 8; i++) {
      f32x4 v = *(const f32x4*)(rp + (i << 2));
      w[g][i * 4 + 0] = v[0];
      w[g][i * 4 + 1] = v[1];
      w[g][i * 4 + 2] = v[2];
      w[g][i * 4 + 3] = v[3];
    }
  }

  unsigned int* cb = &ctr[b * 32];
  const size_t xpb = (size_t)b << 10;

  float xv0 = xp_load(&xp[xpb * 1024 + gu]);
  float xv1 = xp_load(&xp[xpb * 1024 + 256 + gu]);
  float xv2 = xp_load(&xp[xpb * 1024 + 512 + gu]);
  float xv3 = xp_load(&xp[xpb * 1024 + 768 + gu]);

  float c = 0.f;
  float hr[32];

  for (int t = 0; t < 1024; t++) {
    if (t > 0) {
      const unsigned int tgt = 4u * (unsigned int)t;
      // wave-uniform address -> one coalesced dword per poll per wave
      while (__hip_atomic_load(cb, __ATOMIC_RELAXED, __HIP_MEMORY_SCOPE_AGENT) < tgt) {
      }
      const float* hs = hbuf + (size_t)((b << 1) + ((t - 1) & 1)) * 256 + (ks << 5);
#pragma unroll
      for (int i = 0; i < 32; i++)
        hr[i] = __hip_atomic_load(hs + i, __ATOMIC_RELAXED, __HIP_MEMORY_SCOPE_AGENT);
    } else {
#pragma unroll
      for (int i = 0; i < 32; i++) hr[i] = 0.f;
    }

    // prefetch next step's xp (plain cached loads, off critical path)
    float xn0 = 0.f, xn1 = 0.f, xn2 = 0.f, xn3 = 0.f;
    if (t < 1023) {
      const XPT* xr = &xp[(xpb + t + 1) * 1024 + gu];
      xn0 = xp_load(xr);
      xn1 = xp_load(xr + 256);
      xn2 = xp_load(xr + 512);
      xn3 = xp_load(xr + 768);
    }

    float a0 = 0.f, a1 = 0.f, a2 = 0.f, a3 = 0.f;
#pragma unroll
    for (int i = 0; i < 32; i++) {
      a0 = fmaf(w[0][i], hr[i], a0);
      a1 = fmaf(w[1][i], hr[i], a1);
      a2 = fmaf(w[2][i], hr[i], a2);
      a3 = fmaf(w[3][i], hr[i], a3);
    }
#pragma unroll
    for (int d = 1; d < 8; d <<= 1) {
      a0 += __shfl_xor(a0, d, 64);
      a1 += __shfl_xor(a1, d, 64);
      a2 += __shfl_xor(a2, d, 64);
      a3 += __shfl_xor(a3, d, 64);
    }

    // in-register LSTM update (all 8 ks lanes redundantly, deterministic)
    float gf = a0 + xv0, gi = a1 + xv1, gg = a2 + xv2, go = a3 + xv3;
    float f = 1.f / (1.f + __expf(-gf));
    float ii = 1.f / (1.f + __expf(-gi));
    float eg = __expf(2.f * gg);
    float gt = (eg - 1.f) / (eg + 1.f);
    float o = 1.f / (1.f + __expf(-go));
    c = f * c + ii * gt;
    float ec = __expf(2.f * c);
    float tc = (ec - 1.f) / (ec + 1.f);
    float h = o * tc;

    // compact: lane l (l<8) of each wave gathers h of unit wv*8+l (src lane 8*l)
    float hc = __shfl(h, (lane << 3) & 63, 64);
    if (lane < 8) {
      const int gun = (q << 6) + (wv << 3) + lane;
      __hip_atomic_store(&hbuf[(size_t)((b << 1) + (t & 1)) * 256 + gun], hc,
                         __ATOMIC_RELAXED, __HIP_MEMORY_SCOPE_AGENT);
      __builtin_nontemporal_store(hc, &out[(xpb + t) * 256 + gun]);
    }
    if (t == 1023) {
      float cc = __shfl(c, (lane << 3) & 63, 64);
      if (lane < 8) {
        const int gun = (q << 6) + (wv << 3) + lane;
        out[16777216 + b * 256 + gun] = hc;           // h_fin
        out[16777216 + 16384 + b * 256 + gun] = cc;   // c_fin
      }
    }

    xv0 = xn0; xv1 = xn1; xv2 = xn2; xv3 = xn3;

    __syncthreads();  // per-wave s_waitcnt vmcnt(0) before s_barrier: h stores visible
    if (tid == 0)
      __hip_atomic_fetch_add(cb, 1u, __ATOMIC_RELAXED, __HIP_MEMORY_SCOPE_AGENT);
  }
}

extern "C" void kernel_launch(void* const* d_in, const int* in_sizes, int n_in,
                              void* d_out, int out_size, void* d_ws, size_t ws_size,
                              hipStream_t stream) {
  (void)in_sizes; (void)n_in; (void)out_size;
  const float* x = (const float*)d_in[0];
  const float* W = (const float*)d_in[1];
  const float* bias = (const float*)d_in[2];
  float* out = (float*)d_out;
  char* ws = (char*)d_ws;

  unsigned int* Wx2 = (unsigned int*)ws;            // 524288 B
  float* hbuf = (float*)(ws + 524288);              // 131072 B
  unsigned int* ctr = (unsigned int*)(ws + 655360); // 8192 B
  char* xpmem = ws + 1048576;

  const size_t need32 = 1048576 + (size_t)65536 * 1024 * 4;

  hipMemsetAsync(ctr, 0, 8192, stream);
  prep_wx<<<512, 256, 0, stream>>>(W, Wx2);

  if (ws_size >= need32) {
    gemm_xp<float><<<dim3(8, 512), 256, 0, stream>>>(x, Wx2, bias, (float*)xpmem);
    lstm_rec<float><<<256, 512, 0, stream>>>(W, (const float*)xpmem, out, hbuf, ctr);
  } else {
    gemm_xp<unsigned short><<<dim3(8, 512), 256, 0, stream>>>(x, Wx2, bias,
                                                              (unsigned short*)xpmem);
    lstm_rec<unsigned short><<<256, 512, 0, stream>>>(W, (const unsigned short*)xpmem, out,
                                                      hbuf, ctr);
  }
}